// Round 8
// baseline (96.651 us; speedup 1.0000x reference)
//
#include <hip/hip_runtime.h>
#include <math.h>

#define NUM_EMB 512
#define DIMV 65          // 65
#define DD   64          // DIM-1
#define BB   2048
#define NN   256

typedef short short8 __attribute__((ext_vector_type(8)));   // 8 bf16 (4 VGPR)
typedef float f32x4  __attribute__((ext_vector_type(4)));   // MFMA acc

__device__ __forceinline__ float gelu_exact(float x) {
    return 0.5f * x * (1.0f + erff(x * 0.7071067811865475f));
}

// fp32 -> bf16, round-to-nearest-even, deterministic
__device__ __forceinline__ unsigned short f2bf(float f) {
    unsigned u = __builtin_bit_cast(unsigned, f);
    u += 0x7FFFu + ((u >> 16) & 1u);
    return (unsigned short)(u >> 16);
}

// ---------------------------------------------------------------------------
// Kernel 1: build W[e] = H0 @ ... @ H63 (Householder matvec + rank-1 update),
// scale last column, store TRANSPOSED bf16: WgT[e][c][d] = bf16(W[e][d][c]).
// Rows of WgT are 128 B -> 16B-aligned short8 fragment loads in apply_W.
// Echoes r_idx into the out tail.
// ---------------------------------------------------------------------------
__global__ __launch_bounds__(256) void build_W(const float* __restrict__ emb,
                                               const float* __restrict__ flip_sign,
                                               const int*   __restrict__ r_idx,
                                               unsigned short* __restrict__ WgT,
                                               float* __restrict__ out) {
    __shared__ float v_lds[DD * DD];
    __shared__ float s_lds[DD];
    const int e = blockIdx.x;
    const int t = threadIdx.x;
    const int r = t >> 2;
    const int q = t & 3;

    const float* erow = emb + (size_t)e * (DD * DD);
    #pragma unroll
    for (int p = 0; p < 16; ++p) {
        int idx = p * 256 + t;
        v_lds[idx] = gelu_exact(erow[idx]);
    }

    // r_idx passthrough: output 1 lives at out[BB*NN*DIMV + b]
    if (t < 4) {
        int bi = e * 4 + t;
        out[(size_t)BB * NN * DIMV + bi] = (float)r_idx[bi];
    }
    __syncthreads();

    {
        const float* vr = &v_lds[r * DD + q * 16];
        float ss = 0.f;
        #pragma unroll
        for (int k = 0; k < 16; ++k) ss += vr[k] * vr[k];
        ss += __shfl_xor(ss, 1);
        ss += __shfl_xor(ss, 2);
        if (q == 0) s_lds[r] = 2.0f / ss;
    }
    __syncthreads();

    float Wq[16];
    #pragma unroll
    for (int k = 0; k < 16; ++k) Wq[k] = ((q * 16 + k) == r) ? 1.0f : 0.0f;

    // prefetch vv for w=0
    float vv[16], nv[16];
    {
        const float* vr = &v_lds[q * 16];
        *(float4*)&nv[0]  = *(const float4*)&vr[0];
        *(float4*)&nv[4]  = *(const float4*)&vr[4];
        *(float4*)&nv[8]  = *(const float4*)&vr[8];
        *(float4*)&nv[12] = *(const float4*)&vr[12];
    }

    for (int w = 0; w < DD; ++w) {
        #pragma unroll
        for (int k = 0; k < 16; ++k) vv[k] = nv[k];
        if (w < DD - 1) {
            const float* vr = &v_lds[(w + 1) * DD + q * 16];
            *(float4*)&nv[0]  = *(const float4*)&vr[0];
            *(float4*)&nv[4]  = *(const float4*)&vr[4];
            *(float4*)&nv[8]  = *(const float4*)&vr[8];
            *(float4*)&nv[12] = *(const float4*)&vr[12];
        }
        float p0 = Wq[0] * vv[0],  p1 = Wq[1] * vv[1];
        float p2 = Wq[2] * vv[2],  p3 = Wq[3] * vv[3];
        #pragma unroll
        for (int k = 4; k < 16; k += 4) {
            p0 += Wq[k]     * vv[k];
            p1 += Wq[k + 1] * vv[k + 1];
            p2 += Wq[k + 2] * vv[k + 2];
            p3 += Wq[k + 3] * vv[k + 3];
        }
        float p = (p0 + p1) + (p2 + p3);
        p += __shfl_xor(p, 1);
        p += __shfl_xor(p, 2);
        const float sc = s_lds[w] * p;
        #pragma unroll
        for (int k = 0; k < 16; ++k) Wq[k] -= sc * vv[k];
    }

    if (q == 3) Wq[15] *= flip_sign[0];

    // store transposed bf16: WgT[e][c][d] with c = 16q+k, d = r
    unsigned short* wd = WgT + (size_t)e * (DD * DD) + r;
    #pragma unroll
    for (int k = 0; k < 16; ++k)
        wd[(16 * q + k) * DD] = f2bf(Wq[k]);
}

// ---------------------------------------------------------------------------
// Kernel 2 (MFMA, LDS-FREE): out[.,0]=x[.,0]; out[.,1+c]=sum_d x[.,1+d]*W[d][c]
// Block = 256 threads (4 INDEPENDENT waves, no __syncthreads, no LDS).
// Wave w owns rows [rowbase+32w, +32). MFMA fragments are loaded STRAIGHT
// from global:
//  - A frag (rt,kb): lane l needs x[row = base+rt*16+(l&15)][1 + kb*32 +
//    (l>>4)*8 .. +8] -> 8 scalar dword loads (x rows are 4B-aligned only),
//    f2bf in-register. Same global-load count as LDS staging, but zero
//    LDS round-trip / barrier, and loads feed MFMA directly -> compiler
//    must keep them in flight (fixes the VGPR=40 serialization).
//  - B frag (ct,kb): short8 from WgT[e] + (ct*16+(l&15))*64 + kb*32 +
//    (l>>4)*8 -> 16B-aligned, L1/L2-resident (8 KB per embedding).
//  - 16 x mfma_f32_16x16x32_bf16; C/D layout col=lane&15, row=(lane>>4)*4+reg.
//  - col-0 passthrough: lanes 0..31 copy their wave's 32 rows.
// ---------------------------------------------------------------------------
__global__ __launch_bounds__(256) void apply_W(const float* __restrict__ x,
                                               const int*   __restrict__ r_idx,
                                               const unsigned short* __restrict__ WgT,
                                               float* __restrict__ out) {
    const int blk  = blockIdx.x;
    const int b    = blk >> 1;
    const int half = blk & 1;
    const int t    = threadIdx.x;
    const int w    = t >> 6;
    const int l    = t & 63;
    const int lrow  = l & 15;
    const int kslot = l >> 4;

    const size_t wrowbase = (size_t)b * NN + half * 128 + w * 32;  // wave's 32 rows
    const int e = r_idx[b];   // uniform scalar

    // ---- B fragments straight from global (16B aligned) ----
    const unsigned short* wb = WgT + (size_t)e * (DD * DD);
    short8 bfrg[4][2];
    #pragma unroll
    for (int ct = 0; ct < 4; ++ct)
        #pragma unroll
        for (int kb = 0; kb < 2; ++kb)
            bfrg[ct][kb] = *(const short8*)(wb + (ct * 16 + lrow) * DD + kb * 32 + kslot * 8);

    // ---- A fragments straight from global (8 scalar dwords each) ----
    short8 afrg[2][2];
    #pragma unroll
    for (int rt = 0; rt < 2; ++rt) {
        const float* xp = x + (wrowbase + rt * 16 + lrow) * DIMV + 1 + kslot * 8;
        #pragma unroll
        for (int kb = 0; kb < 2; ++kb) {
            float f0 = xp[kb * 32 + 0], f1 = xp[kb * 32 + 1];
            float f2 = xp[kb * 32 + 2], f3 = xp[kb * 32 + 3];
            float f4 = xp[kb * 32 + 4], f5 = xp[kb * 32 + 5];
            float f6 = xp[kb * 32 + 6], f7 = xp[kb * 32 + 7];
            short8 a;
            a[0] = (short)f2bf(f0); a[1] = (short)f2bf(f1);
            a[2] = (short)f2bf(f2); a[3] = (short)f2bf(f3);
            a[4] = (short)f2bf(f4); a[5] = (short)f2bf(f5);
            a[6] = (short)f2bf(f6); a[7] = (short)f2bf(f7);
            afrg[rt][kb] = a;
        }
    }

    // ---- col-0 passthrough: lanes 0..31 cover this wave's 32 rows ----
    float x0v = 0.f;
    if (l < 32) x0v = x[(wrowbase + l) * DIMV];

    // ---- 16 MFMAs, independent accumulators ----
    f32x4 acc[2][4];
    #pragma unroll
    for (int rt = 0; rt < 2; ++rt)
        #pragma unroll
        for (int ct = 0; ct < 4; ++ct) {
            f32x4 c0 = {0.f, 0.f, 0.f, 0.f};
            c0 = __builtin_amdgcn_mfma_f32_16x16x32_bf16(afrg[rt][0], bfrg[ct][0], c0, 0, 0, 0);
            c0 = __builtin_amdgcn_mfma_f32_16x16x32_bf16(afrg[rt][1], bfrg[ct][1], c0, 0, 0, 0);
            acc[rt][ct] = c0;
        }

    if (l < 32) out[(wrowbase + l) * DIMV] = x0v;

    // ---- store: C/D layout col=lane&15, row=(lane>>4)*4+reg ----
    #pragma unroll
    for (int rt = 0; rt < 2; ++rt) {
        const size_t rowb = wrowbase + rt * 16 + kslot * 4;
        #pragma unroll
        for (int ct = 0; ct < 4; ++ct) {
            #pragma unroll
            for (int rg = 0; rg < 4; ++rg) {
                out[(rowb + rg) * DIMV + 1 + ct * 16 + lrow] = acc[rt][ct][rg];
            }
        }
    }
}

extern "C" void kernel_launch(void* const* d_in, const int* in_sizes, int n_in,
                              void* d_out, int out_size, void* d_ws, size_t ws_size,
                              hipStream_t stream) {
    const float* x         = (const float*)d_in[0];
    const int*   r_idx     = (const int*)d_in[1];
    const float* emb       = (const float*)d_in[2];
    const float* flip_sign = (const float*)d_in[3];
    float* out = (float*)d_out;
    unsigned short* WgT = (unsigned short*)d_ws;   // 512*64*64*2 = 4 MB bf16 W^T

    build_W<<<NUM_EMB, 256, 0, stream>>>(emb, flip_sign, r_idx, WgT, out);
    apply_W<<<BB * 2, 256, 0, stream>>>(x, r_idx, WgT, out);
}

// Round 9
// 96.106 us; speedup vs baseline: 1.0057x; 1.0057x over previous
//
#include <hip/hip_runtime.h>
#include <math.h>

#define NUM_EMB 512
#define DIMV 65          // 65
#define DD   64          // DIM-1
#define BB   2048
#define NN   256
#define TPB_TILES 8      // tiles (128 rows) per persistent block
#define GRID_APPLY ((BB * NN) / (128 * TPB_TILES))   // 512 blocks

typedef short short8 __attribute__((ext_vector_type(8)));   // 8 bf16 (4 VGPR)
typedef float f32x4  __attribute__((ext_vector_type(4)));   // MFMA acc

__device__ __forceinline__ float gelu_exact(float x) {
    return 0.5f * x * (1.0f + erff(x * 0.7071067811865475f));
}

// fp32 -> bf16, round-to-nearest-even, deterministic
__device__ __forceinline__ unsigned short f2bf(float f) {
    unsigned u = __builtin_bit_cast(unsigned, f);
    u += 0x7FFFu + ((u >> 16) & 1u);
    return (unsigned short)(u >> 16);
}

// ---------------------------------------------------------------------------
// Kernel 1: build W[e] = H0 @ ... @ H63 (Householder matvec + rank-1 update),
// scale last column, store TRANSPOSED bf16: WgT[e][c][d] = bf16(W[e][d][c]).
// Rows of WgT are 128 B -> 16B-aligned short8 fragment loads in apply_W.
// Echoes r_idx into the out tail.
// ---------------------------------------------------------------------------
__global__ __launch_bounds__(256) void build_W(const float* __restrict__ emb,
                                               const float* __restrict__ flip_sign,
                                               const int*   __restrict__ r_idx,
                                               unsigned short* __restrict__ WgT,
                                               float* __restrict__ out) {
    __shared__ float v_lds[DD * DD];
    __shared__ float s_lds[DD];
    const int e = blockIdx.x;
    const int t = threadIdx.x;
    const int r = t >> 2;
    const int q = t & 3;

    const float* erow = emb + (size_t)e * (DD * DD);
    #pragma unroll
    for (int p = 0; p < 16; ++p) {
        int idx = p * 256 + t;
        v_lds[idx] = gelu_exact(erow[idx]);
    }

    // r_idx passthrough: output 1 lives at out[BB*NN*DIMV + b]
    if (t < 4) {
        int bi = e * 4 + t;
        out[(size_t)BB * NN * DIMV + bi] = (float)r_idx[bi];
    }
    __syncthreads();

    {
        const float* vr = &v_lds[r * DD + q * 16];
        float ss = 0.f;
        #pragma unroll
        for (int k = 0; k < 16; ++k) ss += vr[k] * vr[k];
        ss += __shfl_xor(ss, 1);
        ss += __shfl_xor(ss, 2);
        if (q == 0) s_lds[r] = 2.0f / ss;
    }
    __syncthreads();

    float Wq[16];
    #pragma unroll
    for (int k = 0; k < 16; ++k) Wq[k] = ((q * 16 + k) == r) ? 1.0f : 0.0f;

    float vv[16], nv[16];
    {
        const float* vr = &v_lds[q * 16];
        *(float4*)&nv[0]  = *(const float4*)&vr[0];
        *(float4*)&nv[4]  = *(const float4*)&vr[4];
        *(float4*)&nv[8]  = *(const float4*)&vr[8];
        *(float4*)&nv[12] = *(const float4*)&vr[12];
    }

    for (int w = 0; w < DD; ++w) {
        #pragma unroll
        for (int k = 0; k < 16; ++k) vv[k] = nv[k];
        if (w < DD - 1) {
            const float* vr = &v_lds[(w + 1) * DD + q * 16];
            *(float4*)&nv[0]  = *(const float4*)&vr[0];
            *(float4*)&nv[4]  = *(const float4*)&vr[4];
            *(float4*)&nv[8]  = *(const float4*)&vr[8];
            *(float4*)&nv[12] = *(const float4*)&vr[12];
        }
        float p0 = Wq[0] * vv[0],  p1 = Wq[1] * vv[1];
        float p2 = Wq[2] * vv[2],  p3 = Wq[3] * vv[3];
        #pragma unroll
        for (int k = 4; k < 16; k += 4) {
            p0 += Wq[k]     * vv[k];
            p1 += Wq[k + 1] * vv[k + 1];
            p2 += Wq[k + 2] * vv[k + 2];
            p3 += Wq[k + 3] * vv[k + 3];
        }
        float p = (p0 + p1) + (p2 + p3);
        p += __shfl_xor(p, 1);
        p += __shfl_xor(p, 2);
        const float sc = s_lds[w] * p;
        #pragma unroll
        for (int k = 0; k < 16; ++k) Wq[k] -= sc * vv[k];
    }

    if (q == 3) Wq[15] *= flip_sign[0];

    // store transposed bf16: WgT[e][c][d] with c = 16q+k, d = r
    unsigned short* wd = WgT + (size_t)e * (DD * DD) + r;
    #pragma unroll
    for (int k = 0; k < 16; ++k)
        wd[(16 * q + k) * DD] = f2bf(Wq[k]);
}

// ---------------------------------------------------------------------------
// Kernel 2 (MFMA, persistent, software-pipelined):
//   out[.,0]=x[.,0]; out[.,1+c]=sum_d x[.,1+d]*W[d][c]
// Grid 512 x 256thr. Block owns 8 consecutive 128-row tiles (4 b's). Waves
// are fully independent: wave w owns rows [32w,32w+32) of each tile and a
// private double-buffered 4KB LDS slice -> NO __syncthreads anywhere.
// Per-iteration pipeline (sched_barrier(0)-fenced so the scheduler CANNOT
// sink the load batch to its use -> 32 loads stay in flight across the
// whole compute+store phase of the previous tile):
//   P1: f2bf(va) -> swizzled ds_write (progressively drains tile-i loads)
//   P2: issue B-frags for new b (FIRST, so its vmcnt wait never drains A),
//       then all 32 A-loads for tile i+1, then next col-0 value
//   P3: 4x ds_read_b128 fragments, 16x mfma_f32_16x16x32_bf16, stores
//  - A swizzle byte ^= (row&7)<<4 (R6-proven, 0 conflicts)
//  - B frags straight from global (R8-proven, 16B aligned, L2/L3-resident)
//  - C/D layout (HW-verified): col = lane&15, row = (lane>>4)*4 + reg
// ---------------------------------------------------------------------------
__global__ __launch_bounds__(256) void apply_W(const float* __restrict__ x,
                                               const int*   __restrict__ r_idx,
                                               const unsigned short* __restrict__ WgT,
                                               float* __restrict__ out) {
    __shared__ alignas(16) unsigned char ldsA[4 * 2 * 4096];  // wave x dbuf x 4KB
    const int t = threadIdx.x;
    const int w = t >> 6;
    const int l = t & 63;
    const int lrow  = l & 15;
    const int kslot = l >> 4;

    const size_t blockrow0 = (size_t)blockIdx.x * (TPB_TILES * 128);
    const size_t wrow0     = blockrow0 + (size_t)w * 32;   // wave rows, tile 0
    const int    b0        = blockIdx.x * (TPB_TILES / 2); // 4 b's per block
    const long   tstride   = (long)128 * DIMV;             // floats per tile

    // prefetch the 4 embedding ids (uniform scalars)
    const int e0 = r_idx[b0 + 0];
    const int e1 = r_idx[b0 + 1];
    const int e2 = r_idx[b0 + 2];
    const int e3 = r_idx[b0 + 3];

    const float* xp  = x + wrow0 * DIMV + 1 + l;   // A-stage base (tile 0)
    const float* x0p = x + wrow0 * DIMV;           // col-0 base
    float*       op  = out + wrow0 * DIMV;         // store base

    // ---- prologue: B frags for b0, then tile-0 A loads, then x0 ----
    short8 bfrg[4][2];
    {
        const unsigned short* wb = WgT + (size_t)e0 * (DD * DD);
        #pragma unroll
        for (int ct = 0; ct < 4; ++ct)
            #pragma unroll
            for (int kb = 0; kb < 2; ++kb)
                bfrg[ct][kb] = *(const short8*)(wb + (ct * 16 + lrow) * DD + kb * 32 + kslot * 8);
    }
    float va[32];
    #pragma unroll
    for (int k = 0; k < 32; ++k) va[k] = xp[k * DIMV];
    float x0v = (l < 32) ? x0p[(long)l * DIMV] : 0.f;
    __builtin_amdgcn_sched_barrier(0);

    for (int i = 0; i < TPB_TILES; ++i) {
        // ---- P1: convert + swizzled ds_write of tile i ----
        unsigned char* buf = &ldsA[(w * 2 + (i & 1)) * 4096];
        #pragma unroll
        for (int k = 0; k < 32; ++k) {
            int off = (l * 2) ^ ((k & 7) << 4);
            *(unsigned short*)&buf[k * 128 + off] = f2bf(va[k]);
        }
        __builtin_amdgcn_sched_barrier(0);

        // ---- P2: issue next loads ----
        // B frags for a NEW b (this tile uses them; issued before A-next so
        // waiting on them never drains the A stream)
        if ((i & 1) == 0 && i > 0) {
            const int en = (i >> 1) == 1 ? e1 : ((i >> 1) == 2 ? e2 : e3);
            const unsigned short* wb = WgT + (size_t)en * (DD * DD);
            #pragma unroll
            for (int ct = 0; ct < 4; ++ct)
                #pragma unroll
                for (int kb = 0; kb < 2; ++kb)
                    bfrg[ct][kb] = *(const short8*)(wb + (ct * 16 + lrow) * DD + kb * 32 + kslot * 8);
        }
        float x0n = 0.f;
        if (i + 1 < TPB_TILES) {
            const float* xn = xp + (long)(i + 1) * tstride;
            #pragma unroll
            for (int k = 0; k < 32; ++k) va[k] = xn[k * DIMV];
            if (l < 32) x0n = x0p[(long)(i + 1) * tstride + (long)l * DIMV];
        }
        __builtin_amdgcn_sched_barrier(0);

        // ---- P3: fragments, MFMA, stores for tile i ----
        short8 afrg[2][2];
        #pragma unroll
        for (int rt = 0; rt < 2; ++rt)
            #pragma unroll
            for (int kb = 0; kb < 2; ++kb) {
                int row = rt * 16 + lrow;
                int off = ((kb << 6) | (kslot << 4)) ^ ((row & 7) << 4);
                afrg[rt][kb] = *(const short8*)&buf[row * 128 + off];
            }

        f32x4 acc[2][4];
        #pragma unroll
        for (int rt = 0; rt < 2; ++rt)
            #pragma unroll
            for (int ct = 0; ct < 4; ++ct) {
                f32x4 c0 = {0.f, 0.f, 0.f, 0.f};
                c0 = __builtin_amdgcn_mfma_f32_16x16x32_bf16(afrg[rt][0], bfrg[ct][0], c0, 0, 0, 0);
                c0 = __builtin_amdgcn_mfma_f32_16x16x32_bf16(afrg[rt][1], bfrg[ct][1], c0, 0, 0, 0);
                acc[rt][ct] = c0;
            }

        float* ob = op + (long)i * tstride;
        if (l < 32) ob[(long)l * DIMV] = x0v;          // col-0 passthrough
        #pragma unroll
        for (int rt = 0; rt < 2; ++rt) {
            #pragma unroll
            for (int ct = 0; ct < 4; ++ct)
                #pragma unroll
                for (int rg = 0; rg < 4; ++rg)
                    ob[(rt * 16 + kslot * 4 + rg) * DIMV + 1 + ct * 16 + lrow] = acc[rt][ct][rg];
        }
        x0v = x0n;
    }
}

extern "C" void kernel_launch(void* const* d_in, const int* in_sizes, int n_in,
                              void* d_out, int out_size, void* d_ws, size_t ws_size,
                              hipStream_t stream) {
    const float* x         = (const float*)d_in[0];
    const int*   r_idx     = (const int*)d_in[1];
    const float* emb       = (const float*)d_in[2];
    const float* flip_sign = (const float*)d_in[3];
    float* out = (float*)d_out;
    unsigned short* WgT = (unsigned short*)d_ws;   // 512*64*64*2 = 4 MB bf16 W^T

    build_W<<<NUM_EMB, 256, 0, stream>>>(emb, flip_sign, r_idx, WgT, out);
    apply_W<<<GRID_APPLY, 256, 0, stream>>>(x, r_idx, WgT, out);
}

// Round 10
// 77.133 us; speedup vs baseline: 1.2530x; 1.2460x over previous
//
#include <hip/hip_runtime.h>
#include <math.h>

#define NUM_EMB 512
#define DIMV 65          // 65
#define DD   64          // DIM-1
#define BB   2048
#define NN   256

typedef short short8 __attribute__((ext_vector_type(8)));   // 8 bf16 (4 VGPR)
typedef float f32x4  __attribute__((ext_vector_type(4)));   // MFMA acc

__device__ __forceinline__ float gelu_exact(float x) {
    return 0.5f * x * (1.0f + erff(x * 0.7071067811865475f));
}

// fp32 -> bf16, round-to-nearest-even, deterministic
__device__ __forceinline__ unsigned f2bf_u(float f) {
    unsigned u = __builtin_bit_cast(unsigned, f);
    u += 0x7FFFu + ((u >> 16) & 1u);
    return u >> 16;
}
__device__ __forceinline__ unsigned short f2bf(float f) {
    return (unsigned short)f2bf_u(f);
}

// ---------------------------------------------------------------------------
// Kernel 1: build W[e] = H0 @ ... @ H63 (Householder matvec + rank-1 update),
// scale last column, store TRANSPOSED bf16: WgT[e][c][d] = bf16(W[e][d][c]).
// Rows of WgT are 128 B -> 16B-aligned short8 fragment loads in apply_W.
// Echoes r_idx into the out tail.
// ---------------------------------------------------------------------------
__global__ __launch_bounds__(256) void build_W(const float* __restrict__ emb,
                                               const float* __restrict__ flip_sign,
                                               const int*   __restrict__ r_idx,
                                               unsigned short* __restrict__ WgT,
                                               float* __restrict__ out) {
    __shared__ float v_lds[DD * DD];
    __shared__ float s_lds[DD];
    const int e = blockIdx.x;
    const int t = threadIdx.x;
    const int r = t >> 2;
    const int q = t & 3;

    const float* erow = emb + (size_t)e * (DD * DD);
    #pragma unroll
    for (int p = 0; p < 16; ++p) {
        int idx = p * 256 + t;
        v_lds[idx] = gelu_exact(erow[idx]);
    }

    // r_idx passthrough: output 1 lives at out[BB*NN*DIMV + b]
    if (t < 4) {
        int bi = e * 4 + t;
        out[(size_t)BB * NN * DIMV + bi] = (float)r_idx[bi];
    }
    __syncthreads();

    {
        const float* vr = &v_lds[r * DD + q * 16];
        float ss = 0.f;
        #pragma unroll
        for (int k = 0; k < 16; ++k) ss += vr[k] * vr[k];
        ss += __shfl_xor(ss, 1);
        ss += __shfl_xor(ss, 2);
        if (q == 0) s_lds[r] = 2.0f / ss;
    }
    __syncthreads();

    float Wq[16];
    #pragma unroll
    for (int k = 0; k < 16; ++k) Wq[k] = ((q * 16 + k) == r) ? 1.0f : 0.0f;

    float vv[16], nv[16];
    {
        const float* vr = &v_lds[q * 16];
        *(float4*)&nv[0]  = *(const float4*)&vr[0];
        *(float4*)&nv[4]  = *(const float4*)&vr[4];
        *(float4*)&nv[8]  = *(const float4*)&vr[8];
        *(float4*)&nv[12] = *(const float4*)&vr[12];
    }

    for (int w = 0; w < DD; ++w) {
        #pragma unroll
        for (int k = 0; k < 16; ++k) vv[k] = nv[k];
        if (w < DD - 1) {
            const float* vr = &v_lds[(w + 1) * DD + q * 16];
            *(float4*)&nv[0]  = *(const float4*)&vr[0];
            *(float4*)&nv[4]  = *(const float4*)&vr[4];
            *(float4*)&nv[8]  = *(const float4*)&vr[8];
            *(float4*)&nv[12] = *(const float4*)&vr[12];
        }
        float p0 = Wq[0] * vv[0],  p1 = Wq[1] * vv[1];
        float p2 = Wq[2] * vv[2],  p3 = Wq[3] * vv[3];
        #pragma unroll
        for (int k = 4; k < 16; k += 4) {
            p0 += Wq[k]     * vv[k];
            p1 += Wq[k + 1] * vv[k + 1];
            p2 += Wq[k + 2] * vv[k + 2];
            p3 += Wq[k + 3] * vv[k + 3];
        }
        float p = (p0 + p1) + (p2 + p3);
        p += __shfl_xor(p, 1);
        p += __shfl_xor(p, 2);
        const float sc = s_lds[w] * p;
        #pragma unroll
        for (int k = 0; k < 16; ++k) Wq[k] -= sc * vv[k];
    }

    if (q == 3) Wq[15] *= flip_sign[0];

    // store transposed bf16: WgT[e][c][d] with c = 16q+k, d = r
    unsigned short* wd = WgT + (size_t)e * (DD * DD) + r;
    #pragma unroll
    for (int k = 0; k < 16; ++k)
        wd[(16 * q + k) * DD] = f2bf(Wq[k]);
}

// ---------------------------------------------------------------------------
// Kernel 2 (MFMA, float4 streams): out[.,0]=x[.,0];
//   out[.,1+c]=sum_d x[.,1+d]*W[d][c]
// Block = 256 threads (4 waves), one 128-row tile (half a b). Structure:
//   1. LOAD tile as 2080 contiguous float4 -> flat fp32 LDS image X[8320]
//      (ds_write_b128, 16B aligned). Copy-benchmark load pattern (m13).
//   2. A-frags: 8x ds_read_b32 from X (2-way bank = free) + f2bf pack.
//      B-frags: direct-global short8 from WgT[e] (16B aligned, L2-hot).
//   3. 16x mfma_f32_16x16x32_bf16 (wave w owns rows [32w,32w+32)).
//   4. Epilogue: acc written back INTO X at cols 1..64 (col-0 values from
//      the load phase survive untouched) - per-wave rows, no extra sync.
//   5. __syncthreads, STORE tile as 2080 contiguous float4. Copy-benchmark
//      store pattern.
// vmem instrs/lane: ~25 (vs 66 in R6-R9 dword versions).
// ---------------------------------------------------------------------------
__global__ __launch_bounds__(256) void apply_W(const float* __restrict__ x,
                                               const int*   __restrict__ r_idx,
                                               const unsigned short* __restrict__ WgT,
                                               float* __restrict__ out) {
    __shared__ alignas(16) float X[128 * DIMV];   // 33280 B flat tile image
    const int blk  = blockIdx.x;
    const int b    = blk >> 1;
    const int half = blk & 1;
    const size_t rowbase = (size_t)b * NN + half * 128;
    const int t = threadIdx.x;

    const int e = r_idx[b];   // uniform scalar

    const int w     = t >> 6;
    const int l     = t & 63;
    const int lrow  = l & 15;
    const int kslot = l >> 4;
    const int r0    = w * 32;

    // ---- B fragments straight from global (issued first; L2/L3-hot) ----
    const unsigned short* wb = WgT + (size_t)e * (DD * DD);
    short8 bfrg[4][2];
    #pragma unroll
    for (int ct = 0; ct < 4; ++ct)
        #pragma unroll
        for (int kb = 0; kb < 2; ++kb)
            bfrg[ct][kb] = *(const short8*)(wb + (ct * 16 + lrow) * DD + kb * 32 + kslot * 8);

    // ---- 1. float4 tile load -> LDS flat image ----
    {
        const float4* xs = (const float4*)(x + rowbase * DIMV);  // 16B aligned
        float4* Xv = (float4*)X;
        float4 v[8];
        #pragma unroll
        for (int p = 0; p < 8; ++p) v[p] = xs[p * 256 + t];
        float4 vt;
        if (t < 32) vt = xs[2048 + t];
        #pragma unroll
        for (int p = 0; p < 8; ++p) Xv[p * 256 + t] = v[p];
        if (t < 32) Xv[2048 + t] = vt;
    }
    __syncthreads();

    // ---- 2. A fragments from flat LDS (8x b32 + f2bf pack; 2-way = free) ----
    short8 afrg[2][2];
    #pragma unroll
    for (int rt = 0; rt < 2; ++rt)
        #pragma unroll
        for (int kb = 0; kb < 2; ++kb) {
            const float* xp = &X[(r0 + rt * 16 + lrow) * DIMV + 1 + kb * 32 + kslot * 8];
            union { short8 s; unsigned u[4]; } af;
            #pragma unroll
            for (int j = 0; j < 4; ++j)
                af.u[j] = f2bf_u(xp[2 * j]) | (f2bf_u(xp[2 * j + 1]) << 16);
            afrg[rt][kb] = af.s;
        }

    // ---- 3. 16 MFMAs ----
    f32x4 acc[2][4];
    #pragma unroll
    for (int rt = 0; rt < 2; ++rt)
        #pragma unroll
        for (int ct = 0; ct < 4; ++ct) {
            f32x4 c0 = {0.f, 0.f, 0.f, 0.f};
            c0 = __builtin_amdgcn_mfma_f32_16x16x32_bf16(afrg[rt][0], bfrg[ct][0], c0, 0, 0, 0);
            c0 = __builtin_amdgcn_mfma_f32_16x16x32_bf16(afrg[rt][1], bfrg[ct][1], c0, 0, 0, 0);
            acc[rt][ct] = c0;
        }

    // ---- 4. epilogue: acc -> X cols 1..64 (C/D: col=lane&15, row=(l>>4)*4+reg)
    // wave w touches only its own rows; col-0 slots keep their loaded values.
    #pragma unroll
    for (int rt = 0; rt < 2; ++rt)
        #pragma unroll
        for (int ct = 0; ct < 4; ++ct)
            #pragma unroll
            for (int rg = 0; rg < 4; ++rg)
                X[(r0 + rt * 16 + kslot * 4 + rg) * DIMV + 1 + ct * 16 + lrow] = acc[rt][ct][rg];
    __syncthreads();

    // ---- 5. float4 tile store ----
    {
        float4* og = (float4*)(out + rowbase * DIMV);   // 16B aligned
        const float4* Xv = (const float4*)X;
        #pragma unroll
        for (int p = 0; p < 8; ++p) og[p * 256 + t] = Xv[p * 256 + t];
        if (t < 32) og[2048 + t] = Xv[2048 + t];
    }
}

extern "C" void kernel_launch(void* const* d_in, const int* in_sizes, int n_in,
                              void* d_out, int out_size, void* d_ws, size_t ws_size,
                              hipStream_t stream) {
    const float* x         = (const float*)d_in[0];
    const int*   r_idx     = (const int*)d_in[1];
    const float* emb       = (const float*)d_in[2];
    const float* flip_sign = (const float*)d_in[3];
    float* out = (float*)d_out;
    unsigned short* WgT = (unsigned short*)d_ws;   // 512*64*64*2 = 4 MB bf16 W^T

    build_W<<<NUM_EMB, 256, 0, stream>>>(emb, flip_sign, r_idx, WgT, out);
    apply_W<<<BB * 2, 256, 0, stream>>>(x, r_idx, WgT, out);
}